// Round 6
// baseline (153.519 us; speedup 1.0000x reference)
//
#include <hip/hip_runtime.h>

// Trilinear interp of [64,64,64,64] fp32 volume at 200k points.
// R12: branchless direct gather. R7 measured the direct structure's traffic
// floor (44 MB fetch + 50 MB write vs staged 131+ MB) but was latency-bound;
// R10's pipeline fix failed the post-timing re-poison check (poison bucket
// slots reached float->int / load pipelines ungated). Fix: zero the WHOLE
// buckets array (8.4 MB memset, ~1.3us) each launch -> every slot is
// zero-or-valid, poison never enters arithmetic. Gather is then straight-line
// per group: 2 slots, all 16 corner loads unconditional (addresses provably
// in [0,63]), store target SELECTED (valid ? out[p] : dump scratch) rather
// than masked. No LDS, no barrier, no divergence -> compiler pipelines the
// loads (first consume at vmcnt(8)). Scatter byte-identical to R9/R11.

#define NBUCK   4096          // 16^3 buckets of 4^3 voxels
#define CAP     128           // mean occupancy 48.8
#define OVCAP   8192

typedef float __attribute__((ext_vector_type(4))) fx4;

__device__ __forceinline__ float4 f4mul(float4 a, float s) {
    return make_float4(a.x * s, a.y * s, a.z * s, a.w * s);
}
__device__ __forceinline__ float4 f4fma(float4 a, float s, float4 acc) {
    return make_float4(fmaf(a.x, s, acc.x), fmaf(a.y, s, acc.y),
                       fmaf(a.z, s, acc.z), fmaf(a.w, s, acc.w));
}

__global__ __launch_bounds__(256) void scatter_kernel(
    const float* __restrict__ coords, int* __restrict__ counts,
    float4* __restrict__ buckets, float4* __restrict__ overflow, int n)
{
    int p = blockIdx.x * 256 + threadIdx.x;
    if (p >= n) return;
    float xs = coords[3 * p + 0] * 0.5f;
    float ys = coords[3 * p + 1] * 0.5f;
    float zs = coords[3 * p + 2] * 0.5f;
    int vx = (int)floorf(xs), vy = (int)floorf(ys), vz = (int)floorf(zs);
    int bucket = ((vx >> 2) << 8) | ((vy >> 2) << 4) | (vz >> 2);
    int slot = atomicAdd(&counts[bucket], 1);
    float4 v = make_float4(xs, ys, zs, __int_as_float(p));
    if (slot < CAP) {
        buckets[bucket * CAP + slot] = v;
    } else {
        int o = atomicAdd(&counts[NBUCK], 1);
        if (o < OVCAP) overflow[o] = v;
    }
}

// Corner offsets (float4 units, incl. cvec) + lerp weights. Inputs are
// guaranteed in [0,64) (valid scatter output) or exactly 0 (zeroed slot),
// so floor/ceil-clamp land in [0,63] and all offsets are in-bounds.
struct Corner {
    int o111, o211, o121, o221, o112, o212, o122, o222;
    float wx, wxc, wy, wyc, wz, wzc;
};

__device__ __forceinline__ Corner corner_setup(float4 cs, int cvec) {
    Corner c;
    float x = cs.x, y = cs.y, z = cs.z;
    float fx1 = floorf(x), fx2 = fminf(ceilf(x), 63.0f);
    float fy1 = floorf(y), fy2 = fminf(ceilf(y), 63.0f);
    float fz1 = floorf(z), fz2 = fminf(ceilf(z), 63.0f);
    int bx1 = ((int)fx1) << 12, bx2 = ((int)fx2) << 12;
    int by1 = ((int)fy1) << 6,  by2 = ((int)fy2) << 6;
    int iz1 = (int)fz1,         iz2 = (int)fz2;
    c.o111 = ((bx1 + by1 + iz1) << 4) + cvec;
    c.o211 = ((bx2 + by1 + iz1) << 4) + cvec;
    c.o121 = ((bx1 + by2 + iz1) << 4) + cvec;
    c.o221 = ((bx2 + by2 + iz1) << 4) + cvec;
    c.o112 = ((bx1 + by1 + iz2) << 4) + cvec;
    c.o212 = ((bx2 + by1 + iz2) << 4) + cvec;
    c.o122 = ((bx1 + by2 + iz2) << 4) + cvec;
    c.o222 = ((bx2 + by2 + iz2) << 4) + cvec;
    c.wx = x - fx1; c.wxc = fx2 - x;
    c.wy = y - fy1; c.wyc = fy2 - y;
    c.wz = z - fz1; c.wzc = fz2 - z;
    return c;
}

__device__ __forceinline__ float4 tri_combine(
    const Corner& c,
    float4 q111, float4 q211, float4 q121, float4 q221,
    float4 q112, float4 q212, float4 q122, float4 q222)
{
    float4 ly1v = f4fma(f4fma(q221, c.wx, f4mul(q121, c.wxc)), c.wy,
                        f4mul(f4fma(q211, c.wx, f4mul(q111, c.wxc)), c.wyc));
    float4 ly2v = f4fma(f4fma(q222, c.wx, f4mul(q122, c.wxc)), c.wy,
                        f4mul(f4fma(q212, c.wx, f4mul(q112, c.wxc)), c.wyc));
    return f4fma(ly2v, c.wz, f4mul(ly1v, c.wzc));
}

__device__ __forceinline__ void lerp_global_store(
    const float4* __restrict__ imgv, float4 cs, int cvec,
    float* __restrict__ out)
{
    Corner c = corner_setup(cs, cvec);
    int p = __float_as_int(cs.w);
    float4 q111 = imgv[c.o111], q211 = imgv[c.o211];
    float4 q121 = imgv[c.o121], q221 = imgv[c.o221];
    float4 q112 = imgv[c.o112], q212 = imgv[c.o212];
    float4 q122 = imgv[c.o122], q222 = imgv[c.o222];
    float4 res = tri_combine(c, q111, q211, q121, q221, q112, q212, q122, q222);
    fx4 r; r.x = res.x; r.y = res.y; r.z = res.z; r.w = res.w;
    __builtin_nontemporal_store(r, (fx4*)out + (p << 4) + cvec);
}

__global__ __launch_bounds__(512, 4) void gather_kernel(
    const float* __restrict__ img, const int* __restrict__ counts,
    const float4* __restrict__ buckets, const float4* __restrict__ overflow,
    float* __restrict__ out, fx4* __restrict__ dump)
{
    const float4* __restrict__ imgv = (const float4*)img;
    int cvec = threadIdx.x & 15;
    int grp  = threadIdx.x >> 4;          // 0..31

    if (blockIdx.x < NBUCK) {
        // XCD chunk swizzle: 8 XCDs x 512 contiguous buckets, z-fastest ->
        // concurrent blocks on one XCD are neighbors; corner reads L2-hit.
        int bucket = (blockIdx.x & 7) * 512 + (blockIdx.x >> 3);
        int base = bucket * CAP;

        // All 128 slots are zero-or-valid (buckets array memset each launch),
        // so every load below is unconditional and in-bounds.
        int cnt = min(counts[bucket], CAP);
        float4 cs0 = buckets[base + grp];
        float4 cs1 = buckets[base + grp + 32];

        // --- 2-point straight-line pipeline: issue all 16 gathers ---
        Corner c0 = corner_setup(cs0, cvec);
        float4 a111 = imgv[c0.o111], a211 = imgv[c0.o211];
        float4 a121 = imgv[c0.o121], a221 = imgv[c0.o221];
        float4 a112 = imgv[c0.o112], a212 = imgv[c0.o212];
        float4 a122 = imgv[c0.o122], a222 = imgv[c0.o222];

        Corner c1 = corner_setup(cs1, cvec);
        float4 b111 = imgv[c1.o111], b211 = imgv[c1.o211];
        float4 b121 = imgv[c1.o121], b221 = imgv[c1.o221];
        float4 b112 = imgv[c1.o112], b212 = imgv[c1.o212];
        float4 b122 = imgv[c1.o122], b222 = imgv[c1.o222];

        {   // consume point 0 (first q use -> vmcnt(8), q1 still in flight)
            float4 res = tri_combine(c0, a111, a211, a121, a221,
                                         a112, a212, a122, a222);
            int p = __float_as_int(cs0.w);
            fx4* tgt = (grp < cnt) ? ((fx4*)out + (p << 4) + cvec)
                                   : (dump + threadIdx.x);
            fx4 r; r.x = res.x; r.y = res.y; r.z = res.z; r.w = res.w;
            __builtin_nontemporal_store(r, tgt);
        }
        {   // consume point 1
            float4 res = tri_combine(c1, b111, b211, b121, b221,
                                         b112, b212, b122, b222);
            int p = __float_as_int(cs1.w);
            fx4* tgt = (grp + 32 < cnt) ? ((fx4*)out + (p << 4) + cvec)
                                        : (dump + threadIdx.x);
            fx4 r; r.x = res.x; r.y = res.y; r.z = res.z; r.w = res.w;
            __builtin_nontemporal_store(r, tgt);
        }
        // residual (cnt > 64): ~1.4% of buckets, gated (slots < cnt are valid)
        for (int t = grp + 64; t < cnt; t += 32) {
            float4 cs = buckets[base + t];
            lerp_global_store(imgv, cs, cvec, out);
        }
    } else {
        // overflow points (normally zero): direct global gather
        int ob = blockIdx.x - NBUCK;            // 0..31
        int cnt = min(counts[NBUCK], OVCAP);
        for (int i = (ob << 5) + grp; i < cnt; i += 32 * 32) {
            float4 cs = overflow[i];
            lerp_global_store(imgv, cs, cvec, out);
        }
    }
}

// Fallback (R1 kernel) if workspace too small.
__global__ __launch_bounds__(256) void trilerp_kernel(
    const float* __restrict__ img, const float* __restrict__ coords,
    float* __restrict__ out, int n_points)
{
    int tid = blockIdx.x * 256 + threadIdx.x;
    int p = tid >> 4;
    if (p >= n_points) return;
    int cvec = tid & 15;

    float x = coords[3 * p + 0] * 0.5f;
    float y = coords[3 * p + 1] * 0.5f;
    float z = coords[3 * p + 2] * 0.5f;

    float4 cs = make_float4(x, y, z, __int_as_float(p));
    lerp_global_store((const float4*)img, cs, cvec, out);
}

extern "C" void kernel_launch(void* const* d_in, const int* in_sizes, int n_in,
                              void* d_out, int out_size, void* d_ws, size_t ws_size,
                              hipStream_t stream) {
    const float* img    = (const float*)d_in[0];   // [1,64,64,64,64]
    const float* coords = (const float*)d_in[1];   // [1,N,3]
    float* out = (float*)d_out;                    // [1,N,64]
    int n = in_sizes[1] / 3;

    size_t counts_bytes  = 32768;                                  // 4097 ints
    size_t buckets_off   = counts_bytes;
    size_t buckets_bytes = (size_t)NBUCK * CAP * sizeof(float4);   // 8 MB
    size_t overflow_off  = buckets_off + buckets_bytes;
    size_t overflow_bytes = (size_t)OVCAP * sizeof(float4);        // 128 KB
    size_t dump_off      = overflow_off + overflow_bytes;
    size_t dump_bytes    = 512 * sizeof(fx4);                      // 8 KB
    size_t need          = dump_off + dump_bytes;

    if (ws_size >= need) {
        int*    counts   = (int*)d_ws;
        float4* buckets  = (float4*)((char*)d_ws + buckets_off);
        float4* overflow = (float4*)((char*)d_ws + overflow_off);
        fx4*    dump     = (fx4*)((char*)d_ws + dump_off);

        // Zero counts AND the whole buckets array: every slot becomes
        // zero-or-valid, closing the poison path (R10's failure mode).
        hipMemsetAsync(d_ws, 0, buckets_off + buckets_bytes, stream);
        int pgrid = (n + 255) / 256;
        scatter_kernel<<<pgrid, 256, 0, stream>>>(coords, counts, buckets, overflow, n);
        gather_kernel<<<NBUCK + 32, 512, 0, stream>>>(img, counts, buckets, overflow, out, dump);
    } else {
        int threads = n * 16;
        int grid = (threads + 255) / 256;
        trilerp_kernel<<<grid, 256, 0, stream>>>(img, coords, out, n);
    }
}